// Round 7
// baseline (314.497 us; speedup 1.0000x reference)
//
#include <hip/hip_runtime.h>
#include <hip/hip_bf16.h>
#include <math.h>

#define EPS 1e-5f

typedef __attribute__((ext_vector_type(8))) short bf16x8;
typedef __attribute__((ext_vector_type(4))) float f32x4;

__device__ __forceinline__ unsigned short f2bf(float f) {
    unsigned u = __float_as_uint(f);
    unsigned r = (u + 0x7FFFu + ((u >> 16) & 1u)) >> 16;   // RNE
    return (unsigned short)r;
}
__device__ __forceinline__ unsigned f2bf2(float lo, float hi) {
    return (unsigned)f2bf(lo) | ((unsigned)f2bf(hi) << 16);
}
__device__ __forceinline__ void bfu2(unsigned u, float& lo, float& hi) {
    lo = __uint_as_float(u << 16);
    hi = __uint_as_float(u & 0xFFFF0000u);
}

// ---------- fused prep: x->bf16 | weight pack | deg zero + BN-stat zero ----------
__global__ __launch_bounds__(256) void prep(const float* __restrict__ x,
                                            unsigned short* __restrict__ xbf, int n4,
                                            const float* __restrict__ W0, const float* __restrict__ W1,
                                            const float* __restrict__ W2, const float* __restrict__ W3,
                                            const float* __restrict__ W4, const float* __restrict__ W5,
                                            const float* __restrict__ W6, const float* __restrict__ W7,
                                            const float* __restrict__ W8, unsigned short* __restrict__ Bpack,
                                            int* __restrict__ deg, float* __restrict__ bstatZ, int N,
                                            int nConv, int nPack) {
    int b = blockIdx.x;
    if (b < nConv) {
        int i = b * 256 + threadIdx.x;
        if (i < n4) {
            float4 v = ((const float4*)x)[i];
            ushort4 o = make_ushort4(f2bf(v.x), f2bf(v.y), f2bf(v.z), f2bf(v.w));
            ((ushort4*)xbf)[i] = o;
        }
    } else if (b < nConv + nPack) {
        int t = (b - nConv) * 256 + threadIdx.x;
        if (t < 9 * 16384) {
            int mat = t >> 14, r = t & 16383;
            const float* W;
            switch (mat) {
                case 0: W = W0; break; case 1: W = W1; break; case 2: W = W2; break;
                case 3: W = W3; break; case 4: W = W4; break; case 5: W = W5; break;
                case 6: W = W6; break; case 7: W = W7; break; default: W = W8; break;
            }
            int j = r & 7, lane = (r >> 3) & 63, nt = (r >> 9) & 7, kc = r >> 12;
            int k = kc * 32 + (lane >> 4) * 8 + j;
            int n = (lane & 15) * 8 + nt;
            Bpack[t] = f2bf(W[k * 128 + n]);
        }
    } else {
        int i = (b - nConv - nPack) * 256 + threadIdx.x;
        if (i < N) deg[i] = 0;
        if (i < 4096) bstatZ[i] = 0.f;   // both layers' stat replicas
    }
}

// ---------- MFMA GEMM (single matrix, coalesced epilogue) ----------
template <int ACT, int WBF>
__global__ __launch_bounds__(256) void gemm_mfma(const unsigned short* __restrict__ Abf,
                                                 const unsigned short* __restrict__ Bp,
                                                 const float* __restrict__ bias,
                                                 float* __restrict__ C,
                                                 unsigned short* __restrict__ Cbf, int M) {
    int wave = threadIdx.x >> 6, lane = threadIdx.x & 63;
    int base = blockIdx.x * 64 + wave * 16;
    int m = lane & 15, kg = lane >> 4;
    int arow = base + m; if (arow >= M) arow = M - 1;
    const unsigned short* Aptr = Abf + (size_t)arow * 128 + kg * 8;
    f32x4 acc[8];
#pragma unroll
    for (int nt = 0; nt < 8; ++nt) acc[nt] = (f32x4)(0.f);
#pragma unroll
    for (int kc = 0; kc < 4; ++kc) {
        bf16x8 a = *(const bf16x8*)(Aptr + kc * 32);
        const unsigned short* bp = Bp + (size_t)kc * 4096 + (size_t)lane * 8;
#pragma unroll
        for (int nt = 0; nt < 8; ++nt) {
            bf16x8 b = *(const bf16x8*)(bp + nt * 512);
            acc[nt] = __builtin_amdgcn_mfma_f32_16x16x32_bf16(a, b, acc[nt], 0, 0, 0);
        }
    }
    int col0 = lane & 15;
    int r0 = base + (lane >> 4) * 4;
    float4 bl = *(const float4*)&bias[col0 * 8];
    float4 bh = *(const float4*)&bias[col0 * 8 + 4];
#pragma unroll
    for (int r = 0; r < 4; ++r) {
        int ro = r0 + r;
        if (ro < M) {
            float v0 = acc[0][r] + bl.x, v1 = acc[1][r] + bl.y;
            float v2 = acc[2][r] + bl.z, v3 = acc[3][r] + bl.w;
            float v4 = acc[4][r] + bh.x, v5 = acc[5][r] + bh.y;
            float v6 = acc[6][r] + bh.z, v7 = acc[7][r] + bh.w;
            if (ACT) {
                v0 = fmaxf(v0, 0.f); v1 = fmaxf(v1, 0.f); v2 = fmaxf(v2, 0.f); v3 = fmaxf(v3, 0.f);
                v4 = fmaxf(v4, 0.f); v5 = fmaxf(v5, 0.f); v6 = fmaxf(v6, 0.f); v7 = fmaxf(v7, 0.f);
            }
            size_t o = (size_t)ro * 128 + col0 * 8;
            *(float4*)&C[o]     = make_float4(v0, v1, v2, v3);
            *(float4*)&C[o + 4] = make_float4(v4, v5, v6, v7);
            if (WBF)
                *(uint4*)&Cbf[o] = make_uint4(f2bf2(v0, v1), f2bf2(v2, v3),
                                              f2bf2(v4, v5), f2bf2(v6, v7));
        }
    }
}

// ---------- 4-matrix fused GEMM v14: 32 rows/block, ONE matrix per wave ----------
// v13 paired each MFMA with its own B-load (16 loads -> 16 MFMAs per kc, 64KB
// B-set/wave). Now wave w owns matrix w over 32 rows as 2 row-groups: per kc
// 8 B-loads feed 16 MFMAs (B reuse x2, 32KB/wave). Same acc VGPR (64), same
// accumulation order per output (kc, nt) -> bit-identical results.
// BNPRO=1: BN(l-1) prologue on 32 rows -> hout fp32 in place + bf16 A in LDS.
// Rows >= M do nothing (v11 race lesson); LDS slots zero-filled.
template <int BNPRO>
__global__ __launch_bounds__(256) void gemm4(const unsigned short* __restrict__ Abf,
                                             const float* __restrict__ attn,
                                             const float* __restrict__ hres,
                                             float* __restrict__ hout,
                                             const float* __restrict__ bstat,
                                             const float* __restrict__ gamma,
                                             const float* __restrict__ bbeta,
                                             float invN,
                                             const unsigned short* __restrict__ B0,
                                             const unsigned short* __restrict__ B1,
                                             const unsigned short* __restrict__ B2,
                                             const unsigned short* __restrict__ B3,
                                             const float* __restrict__ b0,
                                             const float* __restrict__ b1,
                                             const float* __restrict__ b2,
                                             const float* __restrict__ b3,
                                             unsigned short* __restrict__ qbf,
                                             unsigned short* __restrict__ kvbf,
                                             unsigned short* __restrict__ xrbf, int M) {
    __shared__ unsigned short As[32][136];   // +8 pad
    __shared__ float sMu[128], sGS[128], sB[128];
    int tid = threadIdx.x;
    int base = blockIdx.x * 32;

    if (BNPRO) {
        if (tid < 128) {
            float s = 0.f, q = 0.f;
#pragma unroll
            for (int rep = 0; rep < 8; ++rep) {
                s += bstat[rep * 128 + tid];
                q += bstat[1024 + rep * 128 + tid];
            }
            float mu = s * invN, var = q * invN - mu * mu;
            sMu[tid] = mu;
            sGS[tid] = gamma[tid] * rsqrtf(var + EPS);
            sB[tid] = bbeta[tid];
        }
        __syncthreads();
#pragma unroll
        for (int j = 0; j < 2; ++j) {
            int s = j * 256 + tid;            // 0..511 = 32 rows x 16 slots
            int row = s >> 4, sl = s & 15;
            int grow = base + row;
            if (grow < M) {
                size_t o = (size_t)grow * 128 + sl * 8;
                float4 a0 = *(const float4*)&attn[o];
                float4 a1 = *(const float4*)&attn[o + 4];
                float4 h0 = *(const float4*)&hres[o];
                float4 h1 = *(const float4*)&hres[o + 4];
                int c = sl * 8;
                float r0 = fmaxf((a0.x - sMu[c+0]) * sGS[c+0] + sB[c+0], 0.f) + h0.x;
                float r1 = fmaxf((a0.y - sMu[c+1]) * sGS[c+1] + sB[c+1], 0.f) + h0.y;
                float r2 = fmaxf((a0.z - sMu[c+2]) * sGS[c+2] + sB[c+2], 0.f) + h0.z;
                float r3 = fmaxf((a0.w - sMu[c+3]) * sGS[c+3] + sB[c+3], 0.f) + h0.w;
                float r4 = fmaxf((a1.x - sMu[c+4]) * sGS[c+4] + sB[c+4], 0.f) + h1.x;
                float r5 = fmaxf((a1.y - sMu[c+5]) * sGS[c+5] + sB[c+5], 0.f) + h1.y;
                float r6 = fmaxf((a1.z - sMu[c+6]) * sGS[c+6] + sB[c+6], 0.f) + h1.z;
                float r7 = fmaxf((a1.w - sMu[c+7]) * sGS[c+7] + sB[c+7], 0.f) + h1.w;
                *(float4*)&hout[o]     = make_float4(r0, r1, r2, r3);
                *(float4*)&hout[o + 4] = make_float4(r4, r5, r6, r7);
                *(uint4*)&As[row][sl * 8] = make_uint4(f2bf2(r0, r1), f2bf2(r2, r3),
                                                       f2bf2(r4, r5), f2bf2(r6, r7));
            } else {
                *(uint4*)&As[row][sl * 8] = make_uint4(0u, 0u, 0u, 0u);
            }
        }
        __syncthreads();
    }

    int wave = tid >> 6, lane = tid & 63;
    int m = lane & 15, kg = lane >> 4;

    // wave-uniform matrix selection (all SGPR)
    const unsigned short* Bp; const float* bp;
    unsigned short* Cp; int rstride, coff;
    if (wave == 0)      { Bp = B0; bp = b0; Cp = qbf;  rstride = 128; coff = 0; }
    else if (wave == 1) { Bp = B1; bp = b1; Cp = kvbf; rstride = 256; coff = 0; }
    else if (wave == 2) { Bp = B2; bp = b2; Cp = kvbf; rstride = 256; coff = 128; }
    else                { Bp = B3; bp = b3; Cp = xrbf; rstride = 128; coff = 0; }

    const unsigned short* Aptr0 = 0;
    const unsigned short* Aptr1 = 0;
    if (!BNPRO) {
        int ar0 = base + m;      if (ar0 >= M) ar0 = M - 1;
        int ar1 = base + 16 + m; if (ar1 >= M) ar1 = M - 1;
        Aptr0 = Abf + (size_t)ar0 * 128 + kg * 8;
        Aptr1 = Abf + (size_t)ar1 * 128 + kg * 8;
    }
    f32x4 acc0[8], acc1[8];
#pragma unroll
    for (int nt = 0; nt < 8; ++nt) { acc0[nt] = (f32x4)(0.f); acc1[nt] = (f32x4)(0.f); }
#pragma unroll
    for (int kc = 0; kc < 4; ++kc) {
        bf16x8 a0, a1;
        if (BNPRO) {
            a0 = *(const bf16x8*)&As[m][kg * 8 + kc * 32];
            a1 = *(const bf16x8*)&As[16 + m][kg * 8 + kc * 32];
        } else {
            a0 = *(const bf16x8*)(Aptr0 + kc * 32);
            a1 = *(const bf16x8*)(Aptr1 + kc * 32);
        }
        size_t boff = (size_t)kc * 4096 + (size_t)lane * 8;
#pragma unroll
        for (int nt = 0; nt < 8; ++nt) {
            bf16x8 b = *(const bf16x8*)(Bp + boff + nt * 512);
            acc0[nt] = __builtin_amdgcn_mfma_f32_16x16x32_bf16(a0, b, acc0[nt], 0, 0, 0);
            acc1[nt] = __builtin_amdgcn_mfma_f32_16x16x32_bf16(a1, b, acc1[nt], 0, 0, 0);
        }
    }
    int col0 = lane & 15;
    float4 bl = *(const float4*)&bp[col0 * 8], bh = *(const float4*)&bp[col0 * 8 + 4];
#pragma unroll
    for (int rg = 0; rg < 2; ++rg) {
        int r0r = base + rg * 16 + (lane >> 4) * 4;
#pragma unroll
        for (int r = 0; r < 4; ++r) {
            int ro = r0r + r;
            if (ro < M) {
                f32x4* A0 = rg ? acc1 : acc0;
                size_t o = (size_t)ro * rstride + coff + col0 * 8;
                *(uint4*)&Cp[o] = make_uint4(
                    f2bf2(A0[0][r] + bl.x, A0[1][r] + bl.y),
                    f2bf2(A0[2][r] + bl.z, A0[3][r] + bl.w),
                    f2bf2(A0[4][r] + bh.x, A0[5][r] + bh.y),
                    f2bf2(A0[6][r] + bh.z, A0[7][r] + bh.w));
            }
        }
    }
}

// ---------- CSR build ----------
__global__ __launch_bounds__(256) void csr_hist(const int* __restrict__ ei,
                                                int* __restrict__ deg, int E) {
    int e = blockIdx.x * 256 + threadIdx.x;
    if (e < E) atomicAdd(&deg[ei[E + e]], 1);
}

__global__ __launch_bounds__(256) void scan_block_sums(const int* __restrict__ deg,
                                                       int* __restrict__ bsums, int N) {
    __shared__ int sd[256];
    int i = blockIdx.x * 256 + threadIdx.x;
    sd[threadIdx.x] = (i < N) ? deg[i] : 0;
    __syncthreads();
    for (int off = 128; off > 0; off >>= 1) {
        if (threadIdx.x < off) sd[threadIdx.x] += sd[threadIdx.x + off];
        __syncthreads();
    }
    if (threadIdx.x == 0) bsums[blockIdx.x] = sd[0];
}

__global__ __launch_bounds__(256) void scan_bsums(const int* __restrict__ bsums,
                                                  int* __restrict__ boff, int nb) {
    __shared__ int sd[256];
    int tid = threadIdx.x;
    int per = (nb + 255) / 256;
    int start = tid * per;
    int s = 0;
    for (int i = 0; i < per; ++i) {
        int idx = start + i;
        if (idx < nb) s += bsums[idx];
    }
    int my = s;
    sd[tid] = s;
    __syncthreads();
    for (int off = 1; off < 256; off <<= 1) {
        int t = (tid >= off) ? sd[tid - off] : 0;
        __syncthreads();
        sd[tid] += t;
        __syncthreads();
    }
    int run = sd[tid] - my;
    for (int i = 0; i < per; ++i) {
        int idx = start + i;
        if (idx < nb) {
            boff[idx] = run;
            run += bsums[idx];
        }
    }
}

__global__ __launch_bounds__(256) void scan_local(const int* __restrict__ deg,
                                                  const int* __restrict__ boff,
                                                  int* __restrict__ rowptr,
                                                  int* __restrict__ wrptr, int N, int E) {
    __shared__ int sd[256];
    int i = blockIdx.x * 256 + threadIdx.x;
    int v = (i < N) ? deg[i] : 0;
    sd[threadIdx.x] = v;
    __syncthreads();
    for (int off = 1; off < 256; off <<= 1) {
        int t = (threadIdx.x >= off) ? sd[threadIdx.x - off] : 0;
        __syncthreads();
        sd[threadIdx.x] += t;
        __syncthreads();
    }
    if (i < N) {
        int excl = sd[threadIdx.x] - v + boff[blockIdx.x];
        rowptr[i] = excl;
        wrptr[i] = excl;
        if (i == N - 1) rowptr[N] = E;
    }
}

__global__ __launch_bounds__(256) void csr_fill(const int* __restrict__ ei,
                                                const float* __restrict__ ea,
                                                int* __restrict__ wrptr,
                                                int2* __restrict__ csr_sw, int E) {
    int e = blockIdx.x * 256 + threadIdx.x;
    if (e >= E) return;
    int tgt = ei[E + e];
    int pos = atomicAdd(&wrptr[tgt], 1);
    csr_sw[pos] = make_int2(ei[e], __float_as_int(ea[e]));
}

// ---------- attention gather (v10 structure: pw-factor + kv 2-ahead) ----------
__global__ __launch_bounds__(256) void attn_gather(const unsigned short* __restrict__ qbf,
                                                   const unsigned short* __restrict__ kvbf,
                                                   const unsigned short* __restrict__ xrbf,
                                                   const int* __restrict__ rowptr,
                                                   const int2* __restrict__ csr_sw,
                                                   const float* __restrict__ Wel,
                                                   const float* __restrict__ Wb,
                                                   float* __restrict__ out,
                                                   float* __restrict__ bsumR,
                                                   float* __restrict__ bsumsqR, int N) {
    __shared__ float sdS[4][128];
    __shared__ float sdQ[4][128];
    int tid = threadIdx.x;
    int n = blockIdx.x * 16 + (tid >> 4);
    int sl = tid & 15;
    int wave = tid >> 6, lane = tid & 63;
    bool live = (n < N);
    int nn = live ? n : (N - 1);

    uint4 qu = ((const uint4*)(qbf + (size_t)nn * 128))[sl];
    float qf[8];
    bfu2(qu.x, qf[0], qf[1]); bfu2(qu.y, qf[2], qf[3]);
    bfu2(qu.z, qf[4], qf[5]); bfu2(qu.w, qf[6], qf[7]);
    float wef[8];
    {
        float4 w0 = ((const float4*)Wel)[sl * 2];
        float4 w1 = ((const float4*)Wel)[sl * 2 + 1];
        wef[0] = w0.x; wef[1] = w0.y; wef[2] = w0.z; wef[3] = w0.w;
        wef[4] = w1.x; wef[5] = w1.y; wef[6] = w1.z; wef[7] = w1.w;
    }
    float qwe = 0.f;
#pragma unroll
    for (int c = 0; c < 8; ++c) qwe += qf[c] * wef[c];
    qwe += __shfl_xor(qwe, 1);
    qwe += __shfl_xor(qwe, 2);

    float l = 0.f, pw = 0.f;
    float acc[8];
#pragma unroll
    for (int c = 0; c < 8; ++c) acc[c] = 0.f;

    int beg = live ? rowptr[nn] : 0;
    int end = live ? rowptr[nn + 1] : 0;

    if (beg < end) {
        int2 sw0 = csr_sw[beg];
        int j1 = (beg + 1 < end) ? beg + 1 : beg;
        int2 sw1 = csr_sw[j1];
        int j2 = (beg + 2 < end) ? beg + 2 : beg;
        int2 sw2 = csr_sw[j2];
        const uint4* r0 = (const uint4*)(kvbf + (size_t)sw0.x * 256);
        uint4 ku0 = r0[sl], vu0 = r0[16 + sl];
        const uint4* r1 = (const uint4*)(kvbf + (size_t)sw1.x * 256);
        uint4 ku1 = r1[sl], vu1 = r1[16 + sl];

        for (int i = beg; i < end; ++i) {
            const uint4* r2 = (const uint4*)(kvbf + (size_t)sw2.x * 256);
            uint4 ku2 = r2[sl], vu2 = r2[16 + sl];
            int j3 = (i + 3 < end) ? i + 3 : beg;
            int2 sw3 = csr_sw[j3];

            float w = __int_as_float(sw0.y);
            float kf[8];
            bfu2(ku0.x, kf[0], kf[1]); bfu2(ku0.y, kf[2], kf[3]);
            bfu2(ku0.z, kf[4], kf[5]); bfu2(ku0.w, kf[6], kf[7]);
            float d = 0.f;
#pragma unroll
            for (int c = 0; c < 8; ++c) d += qf[c] * kf[c];
            d += __shfl_xor(d, 1); d += __shfl_xor(d, 2);
            float p = __expf((d + w * qwe) * 0.17677669529663687f);
            l += p;
            pw += p * w;
            float vf[8];
            bfu2(vu0.x, vf[0], vf[1]); bfu2(vu0.y, vf[2], vf[3]);
            bfu2(vu0.z, vf[4], vf[5]); bfu2(vu0.w, vf[6], vf[7]);
#pragma unroll
            for (int c = 0; c < 8; ++c)
                acc[c] += p * vf[c];

            sw0 = sw1; sw1 = sw2; sw2 = sw3;
            ku0 = ku1; vu0 = vu1;
            ku1 = ku2; vu1 = vu2;
        }
    }

    float inv = (l > 0.f) ? 1.f / l : 0.f;
    float ox[8];
#pragma unroll
    for (int c = 0; c < 8; ++c) ox[c] = (acc[c] + pw * wef[c]) * inv;

    uint4 xu = ((const uint4*)(xrbf + (size_t)nn * 128))[sl];
    float xv[8];
    bfu2(xu.x, xv[0], xv[1]); bfu2(xu.y, xv[2], xv[3]);
    bfu2(xu.z, xv[4], xv[5]); bfu2(xu.w, xv[6], xv[7]);
    float4 b0 = ((const float4*)Wb)[sl * 2];
    float4 b1 = ((const float4*)Wb)[sl * 2 + 1];
    float4 c0 = ((const float4*)(Wb + 128))[sl * 2];
    float4 c1 = ((const float4*)(Wb + 128))[sl * 2 + 1];
    float4 d0 = ((const float4*)(Wb + 256))[sl * 2];
    float4 d1 = ((const float4*)(Wb + 256))[sl * 2 + 1];
    float wb0[8] = {b0.x, b0.y, b0.z, b0.w, b1.x, b1.y, b1.z, b1.w};
    float wb1[8] = {c0.x, c0.y, c0.z, c0.w, c1.x, c1.y, c1.z, c1.w};
    float wb2[8] = {d0.x, d0.y, d0.z, d0.w, d1.x, d1.y, d1.z, d1.w};
    float part = 0.f;
#pragma unroll
    for (int c = 0; c < 8; ++c)
        part += ox[c] * wb0[c] + xv[c] * wb1[c] + (ox[c] - xv[c]) * wb2[c];
    part += __shfl_xor(part, 1); part += __shfl_xor(part, 2);
    part += __shfl_xor(part, 4); part += __shfl_xor(part, 8);
    float beta = 1.f / (1.f + __expf(-part));

    float r[8];
#pragma unroll
    for (int c = 0; c < 8; ++c)
        r[c] = beta * xv[c] + (1.f - beta) * ox[c];

    if (live) {
        ((float4*)(out + (size_t)n * 128))[sl * 2] =
            make_float4(r[0], r[1], r[2], r[3]);
        ((float4*)(out + (size_t)n * 128))[sl * 2 + 1] =
            make_float4(r[4], r[5], r[6], r[7]);
    }

    // ---- fused BN stats (LDS stage + 2 atomics/thread for tid<128) ----
    float s8[8], q8[8];
#pragma unroll
    for (int c = 0; c < 8; ++c) {
        s8[c] = live ? r[c] : 0.f;
        q8[c] = live ? r[c] * r[c] : 0.f;
    }
#pragma unroll
    for (int c = 0; c < 8; ++c) {
        s8[c] += __shfl_xor(s8[c], 16); s8[c] += __shfl_xor(s8[c], 32);
        q8[c] += __shfl_xor(q8[c], 16); q8[c] += __shfl_xor(q8[c], 32);
    }
    if ((lane >> 4) == 0) {
#pragma unroll
        for (int c = 0; c < 8; ++c) {
            sdS[wave][sl * 8 + c] = s8[c];
            sdQ[wave][sl * 8 + c] = q8[c];
        }
    }
    __syncthreads();
    if (tid < 128) {
        float s = sdS[0][tid] + sdS[1][tid] + sdS[2][tid] + sdS[3][tid];
        float q = sdQ[0][tid] + sdQ[1][tid] + sdQ[2][tid] + sdQ[3][tid];
        int rep = blockIdx.x & 7;
        atomicAdd(&bsumR[rep * 128 + tid], s);
        atomicAdd(&bsumsqR[rep * 128 + tid], q);
    }
}

// ---------- BN apply + ReLU + residual (final layer only, writes d_out) ----------
__global__ __launch_bounds__(256) void bn_apply(const float* __restrict__ o,
                                                const float* __restrict__ hres,
                                                float* __restrict__ hout,
                                                const float* __restrict__ bstat,
                                                const float* __restrict__ gamma,
                                                const float* __restrict__ bbeta,
                                                int N, float invN) {
    int i = blockIdx.x * 256 + threadIdx.x;
    if (i >= N * 32) return;
    int c4 = i & 31;
    float4 s = make_float4(0.f, 0.f, 0.f, 0.f), ss = s;
#pragma unroll
    for (int rep = 0; rep < 8; ++rep) {
        float4 sv = ((const float4*)bstat)[rep * 32 + c4];
        float4 qv = ((const float4*)(bstat + 1024))[rep * 32 + c4];
        s.x += sv.x; s.y += sv.y; s.z += sv.z; s.w += sv.w;
        ss.x += qv.x; ss.y += qv.y; ss.z += qv.z; ss.w += qv.w;
    }
    float4 g = ((const float4*)gamma)[c4];
    float4 b = ((const float4*)bbeta)[c4];
    float4 ov = ((const float4*)o)[i];
    float4 hr = ((const float4*)hres)[i];
    float4 r;
    { float mu = s.x * invN, var = ss.x * invN - mu * mu;
      r.x = fmaxf((ov.x - mu) * (g.x * rsqrtf(var + EPS)) + b.x, 0.f) + hr.x; }
    { float mu = s.y * invN, var = ss.y * invN - mu * mu;
      r.y = fmaxf((ov.y - mu) * (g.y * rsqrtf(var + EPS)) + b.y, 0.f) + hr.y; }
    { float mu = s.z * invN, var = ss.z * invN - mu * mu;
      r.z = fmaxf((ov.z - mu) * (g.z * rsqrtf(var + EPS)) + b.z, 0.f) + hr.z; }
    { float mu = s.w * invN, var = ss.w * invN - mu * mu;
      r.w = fmaxf((ov.w - mu) * (g.w * rsqrtf(var + EPS)) + b.w, 0.f) + hr.w; }
    ((float4*)hout)[i] = r;
}

extern "C" void kernel_launch(void* const* d_in, const int* in_sizes, int n_in,
                              void* d_out, int out_size, void* d_ws, size_t ws_size,
                              hipStream_t stream) {
    const float* x     = (const float*)d_in[0];
    const int*   ei    = (const int*)d_in[1];
    const float* ea    = (const float*)d_in[2];
    const float* W_in  = (const float*)d_in[3];
    const float* b_in  = (const float*)d_in[4];
    const float* Wq    = (const float*)d_in[5];
    const float* bq    = (const float*)d_in[6];
    const float* Wk    = (const float*)d_in[7];
    const float* bk    = (const float*)d_in[8];
    const float* Wv    = (const float*)d_in[9];
    const float* bv    = (const float*)d_in[10];
    const float* We    = (const float*)d_in[11];
    const float* Wskip = (const float*)d_in[12];
    const float* bskip = (const float*)d_in[13];
    const float* Wbeta = (const float*)d_in[14];
    const float* bn_g  = (const float*)d_in[15];
    const float* bn_b  = (const float*)d_in[16];

    const int N = in_sizes[0] / 128;
    const int E = in_sizes[1] / 2;

    float* ws = (float*)d_ws;
    unsigned short* Bpack = (unsigned short*)ws;           // 9*16384 bf16 = 73728 floats
    size_t off = 73728;
    unsigned short* xbf  = (unsigned short*)(ws + off);               off += (size_t)N * 64;
    unsigned short* hbf  = (unsigned short*)(ws + off);               off += (size_t)N * 64;
    unsigned short* qbf  = (unsigned short*)(ws + off);               off += (size_t)N * 64;
    unsigned short* kvbf = (unsigned short*)(ws + off);               off += (size_t)N * 128;
    unsigned short* xrbf = (unsigned short*)(ws + off);               off += (size_t)N * 64;
    float* h    = ws + off;  off += (size_t)N * 128;
    float* attn = ws + off;  off += (size_t)N * 128;
    float* bstat = ws + off; off += 4096;                  // [l0: sumR1024|sumsq1024][l1: ...]
    int2* csr_sw = (int2*)(ws + off);  off += (size_t)E * 2;
    int* deg     = (int*)(ws + off);
    int* rowptr  = deg + N;
    int* wrptr   = rowptr + (N + 1);
    int* bsums   = wrptr + N;
    int* boff    = bsums + ((N + 255) / 256 + 1);

    float* bstat0 = bstat;
    float* bstat1 = bstat + 2048;

    dim3 blk(256);
    int gGemm   = (N + 63) / 64;
    int gGemm4  = (N + 31) / 32;
    int gNode16 = (N + 15) / 16;
    int gEdge   = (E + 255) / 256;
    int gApply  = (N * 32 + 255) / 256;
    int nbScan  = (N + 255) / 256;
    float invN = 1.0f / (float)N;

    // ---- fused prep: x->bf16 | weight pack | deg+stat zero ----
    int nConv = gApply;
    int nPack = (9 * 16384 + 255) / 256;
    prep<<<nConv + nPack + nbScan, blk, 0, stream>>>(
        x, xbf, N * 32,
        W_in, Wq, Wk, Wv, Wskip, Wq + 16384, Wk + 16384, Wv + 16384, Wskip + 16384,
        Bpack, deg, bstat, N, nConv, nPack);

    // ---- CSR build ----
    csr_hist<<<gEdge, blk, 0, stream>>>(ei, deg, E);
    scan_block_sums<<<nbScan, blk, 0, stream>>>(deg, bsums, N);
    scan_bsums<<<1, blk, 0, stream>>>(bsums, boff, nbScan);
    scan_local<<<nbScan, blk, 0, stream>>>(deg, boff, rowptr, wrptr, N, E);
    csr_fill<<<gEdge, blk, 0, stream>>>(ei, ea, wrptr, csr_sw, E);

    // ---- input projection (writes h fp32 + hbf bf16) ----
    gemm_mfma<1, 1><<<gGemm, blk, 0, stream>>>(xbf, Bpack + 0 * 16384, b_in, h, hbf, N);

    const unsigned short* Bq0 = Bpack + (size_t)1 * 16384;
    const unsigned short* Bk0 = Bpack + (size_t)2 * 16384;
    const unsigned short* Bv0 = Bpack + (size_t)3 * 16384;
    const unsigned short* Bs0 = Bpack + (size_t)4 * 16384;
    const unsigned short* Bq1 = Bpack + (size_t)5 * 16384;
    const unsigned short* Bk1 = Bpack + (size_t)6 * 16384;
    const unsigned short* Bv1 = Bpack + (size_t)7 * 16384;
    const unsigned short* Bs1 = Bpack + (size_t)8 * 16384;

    // ---- layer 0: 4-projection GEMM (A = hbf) ----
    gemm4<0><<<gGemm4, blk, 0, stream>>>(hbf, nullptr, nullptr, nullptr,
                                         nullptr, nullptr, nullptr, 0.f,
                                         Bq0, Bk0, Bv0, Bs0,
                                         bq, bk, bv, bskip,
                                         qbf, kvbf, xrbf, N);
    attn_gather<<<gNode16, blk, 0, stream>>>(qbf, kvbf, xrbf, rowptr, csr_sw,
                                             We, Wbeta, attn,
                                             bstat0, bstat0 + 1024, N);
    // ---- BN(l0) fused into layer-1 4-projection GEMM (hbf never materialized) ----
    gemm4<1><<<gGemm4, blk, 0, stream>>>(nullptr, attn, h, h,
                                         bstat0, bn_g, bn_b, invN,
                                         Bq1, Bk1, Bv1, Bs1,
                                         bq + 128, bk + 128, bv + 128, bskip + 128,
                                         qbf, kvbf, xrbf, N);
    attn_gather<<<gNode16, blk, 0, stream>>>(qbf, kvbf, xrbf, rowptr, csr_sw,
                                             We + 128, Wbeta + 384, attn,
                                             bstat1, bstat1 + 1024, N);
    // ---- final BN + ReLU + residual -> d_out ----
    bn_apply<<<gApply, blk, 0, stream>>>(attn, h, (float*)d_out,
                                         bstat1, bn_g + 128, bn_b + 128,
                                         N, invN);
}

// Round 9
// 308.783 us; speedup vs baseline: 1.0185x; 1.0185x over previous
//
#include <hip/hip_runtime.h>
#include <hip/hip_bf16.h>
#include <math.h>

#define EPS 1e-5f

typedef __attribute__((ext_vector_type(8))) short bf16x8;
typedef __attribute__((ext_vector_type(4))) float f32x4;

__device__ __forceinline__ unsigned short f2bf(float f) {
    unsigned u = __float_as_uint(f);
    unsigned r = (u + 0x7FFFu + ((u >> 16) & 1u)) >> 16;   // RNE
    return (unsigned short)r;
}
__device__ __forceinline__ unsigned f2bf2(float lo, float hi) {
    return (unsigned)f2bf(lo) | ((unsigned)f2bf(hi) << 16);
}
__device__ __forceinline__ void bfu2(unsigned u, float& lo, float& hi) {
    lo = __uint_as_float(u << 16);
    hi = __uint_as_float(u & 0xFFFF0000u);
}

// ---------- fused prep: x->bf16 | weight pack | deg zero + BN-stat zero ----------
__global__ __launch_bounds__(256) void prep(const float* __restrict__ x,
                                            unsigned short* __restrict__ xbf, int n4,
                                            const float* __restrict__ W0, const float* __restrict__ W1,
                                            const float* __restrict__ W2, const float* __restrict__ W3,
                                            const float* __restrict__ W4, const float* __restrict__ W5,
                                            const float* __restrict__ W6, const float* __restrict__ W7,
                                            const float* __restrict__ W8, unsigned short* __restrict__ Bpack,
                                            int* __restrict__ deg, float* __restrict__ bstatZ, int N,
                                            int nConv, int nPack) {
    int b = blockIdx.x;
    if (b < nConv) {
        int i = b * 256 + threadIdx.x;
        if (i < n4) {
            float4 v = ((const float4*)x)[i];
            ushort4 o = make_ushort4(f2bf(v.x), f2bf(v.y), f2bf(v.z), f2bf(v.w));
            ((ushort4*)xbf)[i] = o;
        }
    } else if (b < nConv + nPack) {
        int t = (b - nConv) * 256 + threadIdx.x;
        if (t < 9 * 16384) {
            int mat = t >> 14, r = t & 16383;
            const float* W;
            switch (mat) {
                case 0: W = W0; break; case 1: W = W1; break; case 2: W = W2; break;
                case 3: W = W3; break; case 4: W = W4; break; case 5: W = W5; break;
                case 6: W = W6; break; case 7: W = W7; break; default: W = W8; break;
            }
            int j = r & 7, lane = (r >> 3) & 63, nt = (r >> 9) & 7, kc = r >> 12;
            int k = kc * 32 + (lane >> 4) * 8 + j;
            int n = (lane & 15) * 8 + nt;
            Bpack[t] = f2bf(W[k * 128 + n]);
        }
    } else {
        int i = (b - nConv - nPack) * 256 + threadIdx.x;
        if (i < N) deg[i] = 0;
        if (i < 4096) bstatZ[i] = 0.f;   // both layers' stat replicas
    }
}

// ---------- MFMA GEMM (single matrix, coalesced epilogue) ----------
template <int ACT, int WBF>
__global__ __launch_bounds__(256) void gemm_mfma(const unsigned short* __restrict__ Abf,
                                                 const unsigned short* __restrict__ Bp,
                                                 const float* __restrict__ bias,
                                                 float* __restrict__ C,
                                                 unsigned short* __restrict__ Cbf, int M) {
    int wave = threadIdx.x >> 6, lane = threadIdx.x & 63;
    int base = blockIdx.x * 64 + wave * 16;
    int m = lane & 15, kg = lane >> 4;
    int arow = base + m; if (arow >= M) arow = M - 1;
    const unsigned short* Aptr = Abf + (size_t)arow * 128 + kg * 8;
    f32x4 acc[8];
#pragma unroll
    for (int nt = 0; nt < 8; ++nt) acc[nt] = (f32x4)(0.f);
#pragma unroll
    for (int kc = 0; kc < 4; ++kc) {
        bf16x8 a = *(const bf16x8*)(Aptr + kc * 32);
        const unsigned short* bp = Bp + (size_t)kc * 4096 + (size_t)lane * 8;
#pragma unroll
        for (int nt = 0; nt < 8; ++nt) {
            bf16x8 b = *(const bf16x8*)(bp + nt * 512);
            acc[nt] = __builtin_amdgcn_mfma_f32_16x16x32_bf16(a, b, acc[nt], 0, 0, 0);
        }
    }
    int col0 = lane & 15;
    int r0 = base + (lane >> 4) * 4;
    float4 bl = *(const float4*)&bias[col0 * 8];
    float4 bh = *(const float4*)&bias[col0 * 8 + 4];
#pragma unroll
    for (int r = 0; r < 4; ++r) {
        int ro = r0 + r;
        if (ro < M) {
            float v0 = acc[0][r] + bl.x, v1 = acc[1][r] + bl.y;
            float v2 = acc[2][r] + bl.z, v3 = acc[3][r] + bl.w;
            float v4 = acc[4][r] + bh.x, v5 = acc[5][r] + bh.y;
            float v6 = acc[6][r] + bh.z, v7 = acc[7][r] + bh.w;
            if (ACT) {
                v0 = fmaxf(v0, 0.f); v1 = fmaxf(v1, 0.f); v2 = fmaxf(v2, 0.f); v3 = fmaxf(v3, 0.f);
                v4 = fmaxf(v4, 0.f); v5 = fmaxf(v5, 0.f); v6 = fmaxf(v6, 0.f); v7 = fmaxf(v7, 0.f);
            }
            size_t o = (size_t)ro * 128 + col0 * 8;
            *(float4*)&C[o]     = make_float4(v0, v1, v2, v3);
            *(float4*)&C[o + 4] = make_float4(v4, v5, v6, v7);
            if (WBF)
                *(uint4*)&Cbf[o] = make_uint4(f2bf2(v0, v1), f2bf2(v2, v3),
                                              f2bf2(v4, v5), f2bf2(v6, v7));
        }
    }
}

// ---------- 4-matrix fused GEMM (v13 partition: 32 rows/block, 2 matrices/wave) ----------
// wave w: rows base+(w&1)*16, matrix-pair (w>>1). acc = 64 VGPR, grid = ceil(M/32).
// BNPRO=1: BN(l-1) prologue on 32 rows; attn input is BF16 (attnb), stats fp32.
// -> writes hout fp32 in place + stages bf16 A rows in LDS.
// Rows >= M do nothing (v11 race lesson); their LDS slots are zero-filled.
template <int BNPRO>
__global__ __launch_bounds__(256) void gemm4(const unsigned short* __restrict__ Abf,
                                             const unsigned short* __restrict__ attnb,
                                             const float* __restrict__ hres,
                                             float* __restrict__ hout,
                                             const float* __restrict__ bstat,
                                             const float* __restrict__ gamma,
                                             const float* __restrict__ bbeta,
                                             float invN,
                                             const unsigned short* __restrict__ B0,
                                             const unsigned short* __restrict__ B1,
                                             const unsigned short* __restrict__ B2,
                                             const unsigned short* __restrict__ B3,
                                             const float* __restrict__ b0,
                                             const float* __restrict__ b1,
                                             const float* __restrict__ b2,
                                             const float* __restrict__ b3,
                                             unsigned short* __restrict__ qbf,
                                             unsigned short* __restrict__ kvbf,
                                             unsigned short* __restrict__ xrbf, int M) {
    __shared__ unsigned short As[32][136];   // +8 pad
    __shared__ float sMu[128], sGS[128], sB[128];
    int tid = threadIdx.x;
    int base = blockIdx.x * 32;

    if (BNPRO) {
        if (tid < 128) {
            float s = 0.f, q = 0.f;
#pragma unroll
            for (int rep = 0; rep < 8; ++rep) {
                s += bstat[rep * 128 + tid];
                q += bstat[1024 + rep * 128 + tid];
            }
            float mu = s * invN, var = q * invN - mu * mu;
            sMu[tid] = mu;
            sGS[tid] = gamma[tid] * rsqrtf(var + EPS);
            sB[tid] = bbeta[tid];
        }
        __syncthreads();
#pragma unroll
        for (int j = 0; j < 2; ++j) {
            int s = j * 256 + tid;            // 0..511 = 32 rows x 16 slots
            int row = s >> 4, sl = s & 15;
            int grow = base + row;
            if (grow < M) {
                size_t o = (size_t)grow * 128 + sl * 8;
                uint4 au = *(const uint4*)&attnb[o];
                float a0, a1, a2, a3, a4, a5, a6, a7;
                bfu2(au.x, a0, a1); bfu2(au.y, a2, a3);
                bfu2(au.z, a4, a5); bfu2(au.w, a6, a7);
                float4 h0 = *(const float4*)&hres[o];
                float4 h1 = *(const float4*)&hres[o + 4];
                int c = sl * 8;
                float r0 = fmaxf((a0 - sMu[c+0]) * sGS[c+0] + sB[c+0], 0.f) + h0.x;
                float r1 = fmaxf((a1 - sMu[c+1]) * sGS[c+1] + sB[c+1], 0.f) + h0.y;
                float r2 = fmaxf((a2 - sMu[c+2]) * sGS[c+2] + sB[c+2], 0.f) + h0.z;
                float r3 = fmaxf((a3 - sMu[c+3]) * sGS[c+3] + sB[c+3], 0.f) + h0.w;
                float r4 = fmaxf((a4 - sMu[c+4]) * sGS[c+4] + sB[c+4], 0.f) + h1.x;
                float r5 = fmaxf((a5 - sMu[c+5]) * sGS[c+5] + sB[c+5], 0.f) + h1.y;
                float r6 = fmaxf((a6 - sMu[c+6]) * sGS[c+6] + sB[c+6], 0.f) + h1.z;
                float r7 = fmaxf((a7 - sMu[c+7]) * sGS[c+7] + sB[c+7], 0.f) + h1.w;
                *(float4*)&hout[o]     = make_float4(r0, r1, r2, r3);
                *(float4*)&hout[o + 4] = make_float4(r4, r5, r6, r7);
                *(uint4*)&As[row][sl * 8] = make_uint4(f2bf2(r0, r1), f2bf2(r2, r3),
                                                       f2bf2(r4, r5), f2bf2(r6, r7));
            } else {
                *(uint4*)&As[row][sl * 8] = make_uint4(0u, 0u, 0u, 0u);
            }
        }
        __syncthreads();
    }

    int wave = tid >> 6, lane = tid & 63;
    int rg = wave & 1;              // row group (0..1)
    int mp = wave >> 1;             // matrix pair (0: q/k, 1: v/skip)
    int wbase = base + rg * 16;
    int m = lane & 15, kg = lane >> 4;
    const unsigned short* Aptr = 0;
    if (!BNPRO) {
        int arow = wbase + m; if (arow >= M) arow = M - 1;
        Aptr = Abf + (size_t)arow * 128 + kg * 8;
    }
    const unsigned short* Bx = mp ? B2 : B0;
    const unsigned short* By = mp ? B3 : B1;
    f32x4 ax[8], ay[8];
#pragma unroll
    for (int nt = 0; nt < 8; ++nt) { ax[nt] = (f32x4)(0.f); ay[nt] = (f32x4)(0.f); }
#pragma unroll
    for (int kc = 0; kc < 4; ++kc) {
        bf16x8 a;
        if (BNPRO) a = *(const bf16x8*)&As[rg * 16 + m][kg * 8 + kc * 32];
        else       a = *(const bf16x8*)(Aptr + kc * 32);
        size_t boff = (size_t)kc * 4096 + (size_t)lane * 8;
#pragma unroll
        for (int nt = 0; nt < 8; ++nt) {
            bf16x8 wx = *(const bf16x8*)(Bx + boff + nt * 512);
            ax[nt] = __builtin_amdgcn_mfma_f32_16x16x32_bf16(a, wx, ax[nt], 0, 0, 0);
            bf16x8 wy = *(const bf16x8*)(By + boff + nt * 512);
            ay[nt] = __builtin_amdgcn_mfma_f32_16x16x32_bf16(a, wy, ay[nt], 0, 0, 0);
        }
    }
    int col0 = lane & 15;
    int r0r = wbase + (lane >> 4) * 4;
    const float* bxp = mp ? b2 : b0;
    const float* byp = mp ? b3 : b1;
    float4 bxl = *(const float4*)&bxp[col0 * 8], bxh = *(const float4*)&bxp[col0 * 8 + 4];
    float4 byl = *(const float4*)&byp[col0 * 8], byh = *(const float4*)&byp[col0 * 8 + 4];
#pragma unroll
    for (int r = 0; r < 4; ++r) {
        int ro = r0r + r;
        if (ro < M) {
            size_t qo = (size_t)ro * 128 + col0 * 8;
            size_t kvo = (size_t)ro * 256 + col0 * 8;
            uint4 ox = make_uint4(
                f2bf2(ax[0][r] + bxl.x, ax[1][r] + bxl.y), f2bf2(ax[2][r] + bxl.z, ax[3][r] + bxl.w),
                f2bf2(ax[4][r] + bxh.x, ax[5][r] + bxh.y), f2bf2(ax[6][r] + bxh.z, ax[7][r] + bxh.w));
            uint4 oy = make_uint4(
                f2bf2(ay[0][r] + byl.x, ay[1][r] + byl.y), f2bf2(ay[2][r] + byl.z, ay[3][r] + byl.w),
                f2bf2(ay[4][r] + byh.x, ay[5][r] + byh.y), f2bf2(ay[6][r] + byh.z, ay[7][r] + byh.w));
            if (mp == 0) {
                *(uint4*)&qbf[qo] = ox;           // q
                *(uint4*)&kvbf[kvo] = oy;         // k
            } else {
                *(uint4*)&kvbf[kvo + 128] = ox;   // v
                *(uint4*)&xrbf[qo] = oy;          // skip
            }
        }
    }
}

// ---------- CSR build ----------
__global__ __launch_bounds__(256) void csr_hist(const int* __restrict__ ei,
                                                int* __restrict__ deg, int E) {
    int e = blockIdx.x * 256 + threadIdx.x;
    if (e < E) atomicAdd(&deg[ei[E + e]], 1);
}

__global__ __launch_bounds__(256) void scan_block_sums(const int* __restrict__ deg,
                                                       int* __restrict__ bsums, int N) {
    __shared__ int sd[256];
    int i = blockIdx.x * 256 + threadIdx.x;
    sd[threadIdx.x] = (i < N) ? deg[i] : 0;
    __syncthreads();
    for (int off = 128; off > 0; off >>= 1) {
        if (threadIdx.x < off) sd[threadIdx.x] += sd[threadIdx.x + off];
        __syncthreads();
    }
    if (threadIdx.x == 0) bsums[blockIdx.x] = sd[0];
}

__global__ __launch_bounds__(256) void scan_bsums(const int* __restrict__ bsums,
                                                  int* __restrict__ boff, int nb) {
    __shared__ int sd[256];
    int tid = threadIdx.x;
    int per = (nb + 255) / 256;
    int start = tid * per;
    int s = 0;
    for (int i = 0; i < per; ++i) {
        int idx = start + i;
        if (idx < nb) s += bsums[idx];
    }
    int my = s;
    sd[tid] = s;
    __syncthreads();
    for (int off = 1; off < 256; off <<= 1) {
        int t = (tid >= off) ? sd[tid - off] : 0;
        __syncthreads();
        sd[tid] += t;
        __syncthreads();
    }
    int run = sd[tid] - my;
    for (int i = 0; i < per; ++i) {
        int idx = start + i;
        if (idx < nb) {
            boff[idx] = run;
            run += bsums[idx];
        }
    }
}

__global__ __launch_bounds__(256) void scan_local(const int* __restrict__ deg,
                                                  const int* __restrict__ boff,
                                                  int* __restrict__ rowptr,
                                                  int* __restrict__ wrptr, int N, int E) {
    __shared__ int sd[256];
    int i = blockIdx.x * 256 + threadIdx.x;
    int v = (i < N) ? deg[i] : 0;
    sd[threadIdx.x] = v;
    __syncthreads();
    for (int off = 1; off < 256; off <<= 1) {
        int t = (threadIdx.x >= off) ? sd[threadIdx.x - off] : 0;
        __syncthreads();
        sd[threadIdx.x] += t;
        __syncthreads();
    }
    if (i < N) {
        int excl = sd[threadIdx.x] - v + boff[blockIdx.x];
        rowptr[i] = excl;
        wrptr[i] = excl;
        if (i == N - 1) rowptr[N] = E;
    }
}

__global__ __launch_bounds__(256) void csr_fill(const int* __restrict__ ei,
                                                const float* __restrict__ ea,
                                                int* __restrict__ wrptr,
                                                int2* __restrict__ csr_sw, int E) {
    int e = blockIdx.x * 256 + threadIdx.x;
    if (e >= E) return;
    int tgt = ei[E + e];
    int pos = atomicAdd(&wrptr[tgt], 1);
    csr_sw[pos] = make_int2(ei[e], __float_as_int(ea[e]));
}

// ---------- attention gather (v10 structure), OUT = bf16 ----------
__global__ __launch_bounds__(256) void attn_gather(const unsigned short* __restrict__ qbf,
                                                   const unsigned short* __restrict__ kvbf,
                                                   const unsigned short* __restrict__ xrbf,
                                                   const int* __restrict__ rowptr,
                                                   const int2* __restrict__ csr_sw,
                                                   const float* __restrict__ Wel,
                                                   const float* __restrict__ Wb,
                                                   unsigned short* __restrict__ out,
                                                   float* __restrict__ bsumR,
                                                   float* __restrict__ bsumsqR, int N) {
    __shared__ float sdS[4][128];
    __shared__ float sdQ[4][128];
    int tid = threadIdx.x;
    int n = blockIdx.x * 16 + (tid >> 4);
    int sl = tid & 15;
    int wave = tid >> 6, lane = tid & 63;
    bool live = (n < N);
    int nn = live ? n : (N - 1);

    uint4 qu = ((const uint4*)(qbf + (size_t)nn * 128))[sl];
    float qf[8];
    bfu2(qu.x, qf[0], qf[1]); bfu2(qu.y, qf[2], qf[3]);
    bfu2(qu.z, qf[4], qf[5]); bfu2(qu.w, qf[6], qf[7]);
    float wef[8];
    {
        float4 w0 = ((const float4*)Wel)[sl * 2];
        float4 w1 = ((const float4*)Wel)[sl * 2 + 1];
        wef[0] = w0.x; wef[1] = w0.y; wef[2] = w0.z; wef[3] = w0.w;
        wef[4] = w1.x; wef[5] = w1.y; wef[6] = w1.z; wef[7] = w1.w;
    }
    float qwe = 0.f;
#pragma unroll
    for (int c = 0; c < 8; ++c) qwe += qf[c] * wef[c];
    qwe += __shfl_xor(qwe, 1);
    qwe += __shfl_xor(qwe, 2);

    float l = 0.f, pw = 0.f;
    float acc[8];
#pragma unroll
    for (int c = 0; c < 8; ++c) acc[c] = 0.f;

    int beg = live ? rowptr[nn] : 0;
    int end = live ? rowptr[nn + 1] : 0;

    if (beg < end) {
        int2 sw0 = csr_sw[beg];
        int j1 = (beg + 1 < end) ? beg + 1 : beg;
        int2 sw1 = csr_sw[j1];
        int j2 = (beg + 2 < end) ? beg + 2 : beg;
        int2 sw2 = csr_sw[j2];
        const uint4* r0 = (const uint4*)(kvbf + (size_t)sw0.x * 256);
        uint4 ku0 = r0[sl], vu0 = r0[16 + sl];
        const uint4* r1 = (const uint4*)(kvbf + (size_t)sw1.x * 256);
        uint4 ku1 = r1[sl], vu1 = r1[16 + sl];

        for (int i = beg; i < end; ++i) {
            const uint4* r2 = (const uint4*)(kvbf + (size_t)sw2.x * 256);
            uint4 ku2 = r2[sl], vu2 = r2[16 + sl];
            int j3 = (i + 3 < end) ? i + 3 : beg;
            int2 sw3 = csr_sw[j3];

            float w = __int_as_float(sw0.y);
            float kf[8];
            bfu2(ku0.x, kf[0], kf[1]); bfu2(ku0.y, kf[2], kf[3]);
            bfu2(ku0.z, kf[4], kf[5]); bfu2(ku0.w, kf[6], kf[7]);
            float d = 0.f;
#pragma unroll
            for (int c = 0; c < 8; ++c) d += qf[c] * kf[c];
            d += __shfl_xor(d, 1); d += __shfl_xor(d, 2);
            float p = __expf((d + w * qwe) * 0.17677669529663687f);
            l += p;
            pw += p * w;
            float vf[8];
            bfu2(vu0.x, vf[0], vf[1]); bfu2(vu0.y, vf[2], vf[3]);
            bfu2(vu0.z, vf[4], vf[5]); bfu2(vu0.w, vf[6], vf[7]);
#pragma unroll
            for (int c = 0; c < 8; ++c)
                acc[c] += p * vf[c];

            sw0 = sw1; sw1 = sw2; sw2 = sw3;
            ku0 = ku1; vu0 = vu1;
            ku1 = ku2; vu1 = vu2;
        }
    }

    float inv = (l > 0.f) ? 1.f / l : 0.f;
    float ox[8];
#pragma unroll
    for (int c = 0; c < 8; ++c) ox[c] = (acc[c] + pw * wef[c]) * inv;

    uint4 xu = ((const uint4*)(xrbf + (size_t)nn * 128))[sl];
    float xv[8];
    bfu2(xu.x, xv[0], xv[1]); bfu2(xu.y, xv[2], xv[3]);
    bfu2(xu.z, xv[4], xv[5]); bfu2(xu.w, xv[6], xv[7]);
    float4 b0 = ((const float4*)Wb)[sl * 2];
    float4 b1 = ((const float4*)Wb)[sl * 2 + 1];
    float4 c0 = ((const float4*)(Wb + 128))[sl * 2];
    float4 c1 = ((const float4*)(Wb + 128))[sl * 2 + 1];
    float4 d0 = ((const float4*)(Wb + 256))[sl * 2];
    float4 d1 = ((const float4*)(Wb + 256))[sl * 2 + 1];
    float wb0[8] = {b0.x, b0.y, b0.z, b0.w, b1.x, b1.y, b1.z, b1.w};
    float wb1[8] = {c0.x, c0.y, c0.z, c0.w, c1.x, c1.y, c1.z, c1.w};
    float wb2[8] = {d0.x, d0.y, d0.z, d0.w, d1.x, d1.y, d1.z, d1.w};
    float part = 0.f;
#pragma unroll
    for (int c = 0; c < 8; ++c)
        part += ox[c] * wb0[c] + xv[c] * wb1[c] + (ox[c] - xv[c]) * wb2[c];
    part += __shfl_xor(part, 1); part += __shfl_xor(part, 2);
    part += __shfl_xor(part, 4); part += __shfl_xor(part, 8);
    float beta = 1.f / (1.f + __expf(-part));

    float r[8];
#pragma unroll
    for (int c = 0; c < 8; ++c)
        r[c] = beta * xv[c] + (1.f - beta) * ox[c];

    if (live) {
        *(uint4*)&out[(size_t)n * 128 + sl * 8] =
            make_uint4(f2bf2(r[0], r[1]), f2bf2(r[2], r[3]),
                       f2bf2(r[4], r[5]), f2bf2(r[6], r[7]));
    }

    // ---- fused BN stats on fp32 r (LDS stage + 2 atomics/thread for tid<128) ----
    float s8[8], q8[8];
#pragma unroll
    for (int c = 0; c < 8; ++c) {
        s8[c] = live ? r[c] : 0.f;
        q8[c] = live ? r[c] * r[c] : 0.f;
    }
#pragma unroll
    for (int c = 0; c < 8; ++c) {
        s8[c] += __shfl_xor(s8[c], 16); s8[c] += __shfl_xor(s8[c], 32);
        q8[c] += __shfl_xor(q8[c], 16); q8[c] += __shfl_xor(q8[c], 32);
    }
    if ((lane >> 4) == 0) {
#pragma unroll
        for (int c = 0; c < 8; ++c) {
            sdS[wave][sl * 8 + c] = s8[c];
            sdQ[wave][sl * 8 + c] = q8[c];
        }
    }
    __syncthreads();
    if (tid < 128) {
        float s = sdS[0][tid] + sdS[1][tid] + sdS[2][tid] + sdS[3][tid];
        float q = sdQ[0][tid] + sdQ[1][tid] + sdQ[2][tid] + sdQ[3][tid];
        int rep = blockIdx.x & 7;
        atomicAdd(&bsumR[rep * 128 + tid], s);
        atomicAdd(&bsumsqR[rep * 128 + tid], q);
    }
}

// ---------- BN apply + ReLU + residual (final layer, bf16 attn in, writes d_out) ----------
__global__ __launch_bounds__(256) void bn_apply(const unsigned short* __restrict__ o,
                                                const float* __restrict__ hres,
                                                float* __restrict__ hout,
                                                const float* __restrict__ bstat,
                                                const float* __restrict__ gamma,
                                                const float* __restrict__ bbeta,
                                                int N, float invN) {
    int i = blockIdx.x * 256 + threadIdx.x;
    if (i >= N * 32) return;
    int c4 = i & 31;
    float4 s = make_float4(0.f, 0.f, 0.f, 0.f), ss = s;
#pragma unroll
    for (int rep = 0; rep < 8; ++rep) {
        float4 sv = ((const float4*)bstat)[rep * 32 + c4];
        float4 qv = ((const float4*)(bstat + 1024))[rep * 32 + c4];
        s.x += sv.x; s.y += sv.y; s.z += sv.z; s.w += sv.w;
        ss.x += qv.x; ss.y += qv.y; ss.z += qv.z; ss.w += qv.w;
    }
    float4 g = ((const float4*)gamma)[c4];
    float4 b = ((const float4*)bbeta)[c4];
    uint2 ou = *(const uint2*)&o[(size_t)i * 4];
    float o0, o1, o2, o3;
    bfu2(ou.x, o0, o1); bfu2(ou.y, o2, o3);
    float4 hr = ((const float4*)hres)[i];
    float4 r;
    { float mu = s.x * invN, var = ss.x * invN - mu * mu;
      r.x = fmaxf((o0 - mu) * (g.x * rsqrtf(var + EPS)) + b.x, 0.f) + hr.x; }
    { float mu = s.y * invN, var = ss.y * invN - mu * mu;
      r.y = fmaxf((o1 - mu) * (g.y * rsqrtf(var + EPS)) + b.y, 0.f) + hr.y; }
    { float mu = s.z * invN, var = ss.z * invN - mu * mu;
      r.z = fmaxf((o2 - mu) * (g.z * rsqrtf(var + EPS)) + b.z, 0.f) + hr.z; }
    { float mu = s.w * invN, var = ss.w * invN - mu * mu;
      r.w = fmaxf((o3 - mu) * (g.w * rsqrtf(var + EPS)) + b.w, 0.f) + hr.w; }
    ((float4*)hout)[i] = r;
}

extern "C" void kernel_launch(void* const* d_in, const int* in_sizes, int n_in,
                              void* d_out, int out_size, void* d_ws, size_t ws_size,
                              hipStream_t stream) {
    const float* x     = (const float*)d_in[0];
    const int*   ei    = (const int*)d_in[1];
    const float* ea    = (const float*)d_in[2];
    const float* W_in  = (const float*)d_in[3];
    const float* b_in  = (const float*)d_in[4];
    const float* Wq    = (const float*)d_in[5];
    const float* bq    = (const float*)d_in[6];
    const float* Wk    = (const float*)d_in[7];
    const float* bk    = (const float*)d_in[8];
    const float* Wv    = (const float*)d_in[9];
    const float* bv    = (const float*)d_in[10];
    const float* We    = (const float*)d_in[11];
    const float* Wskip = (const float*)d_in[12];
    const float* bskip = (const float*)d_in[13];
    const float* Wbeta = (const float*)d_in[14];
    const float* bn_g  = (const float*)d_in[15];
    const float* bn_b  = (const float*)d_in[16];

    const int N = in_sizes[0] / 128;
    const int E = in_sizes[1] / 2;

    float* ws = (float*)d_ws;
    unsigned short* Bpack = (unsigned short*)ws;           // 9*16384 bf16 = 73728 floats
    size_t off = 73728;
    unsigned short* xbf  = (unsigned short*)(ws + off);               off += (size_t)N * 64;
    unsigned short* hbf  = (unsigned short*)(ws + off);               off += (size_t)N * 64;
    unsigned short* qbf  = (unsigned short*)(ws + off);               off += (size_t)N * 64;
    unsigned short* kvbf = (unsigned short*)(ws + off);               off += (size_t)N * 128;
    unsigned short* xrbf = (unsigned short*)(ws + off);               off += (size_t)N * 64;
    float* h    = ws + off;  off += (size_t)N * 128;
    unsigned short* attnb = (unsigned short*)(ws + off);  off += (size_t)N * 64;   // bf16 attn
    float* bstat = ws + off; off += 4096;                  // [l0: sumR1024|sumsq1024][l1: ...]
    int2* csr_sw = (int2*)(ws + off);  off += (size_t)E * 2;
    int* deg     = (int*)(ws + off);
    int* rowptr  = deg + N;
    int* wrptr   = rowptr + (N + 1);
    int* bsums   = wrptr + N;
    int* boff    = bsums + ((N + 255) / 256 + 1);

    float* bstat0 = bstat;
    float* bstat1 = bstat + 2048;

    dim3 blk(256);
    int gGemm   = (N + 63) / 64;
    int gGemm4  = (N + 31) / 32;
    int gNode16 = (N + 15) / 16;
    int gEdge   = (E + 255) / 256;
    int gApply  = (N * 32 + 255) / 256;
    int nbScan  = (N + 255) / 256;
    float invN = 1.0f / (float)N;

    // ---- fused prep: x->bf16 | weight pack | deg+stat zero ----
    int nConv = gApply;
    int nPack = (9 * 16384 + 255) / 256;
    prep<<<nConv + nPack + nbScan, blk, 0, stream>>>(
        x, xbf, N * 32,
        W_in, Wq, Wk, Wv, Wskip, Wq + 16384, Wk + 16384, Wv + 16384, Wskip + 16384,
        Bpack, deg, bstat, N, nConv, nPack);

    // ---- CSR build ----
    csr_hist<<<gEdge, blk, 0, stream>>>(ei, deg, E);
    scan_block_sums<<<nbScan, blk, 0, stream>>>(deg, bsums, N);
    scan_bsums<<<1, blk, 0, stream>>>(bsums, boff, nbScan);
    scan_local<<<nbScan, blk, 0, stream>>>(deg, boff, rowptr, wrptr, N, E);
    csr_fill<<<gEdge, blk, 0, stream>>>(ei, ea, wrptr, csr_sw, E);

    // ---- input projection (writes h fp32 + hbf bf16) ----
    gemm_mfma<1, 1><<<gGemm, blk, 0, stream>>>(xbf, Bpack + 0 * 16384, b_in, h, hbf, N);

    const unsigned short* Bq0 = Bpack + (size_t)1 * 16384;
    const unsigned short* Bk0 = Bpack + (size_t)2 * 16384;
    const unsigned short* Bv0 = Bpack + (size_t)3 * 16384;
    const unsigned short* Bs0 = Bpack + (size_t)4 * 16384;
    const unsigned short* Bq1 = Bpack + (size_t)5 * 16384;
    const unsigned short* Bk1 = Bpack + (size_t)6 * 16384;
    const unsigned short* Bv1 = Bpack + (size_t)7 * 16384;
    const unsigned short* Bs1 = Bpack + (size_t)8 * 16384;

    // ---- layer 0: 4-projection GEMM (A = hbf) ----
    gemm4<0><<<gGemm4, blk, 0, stream>>>(hbf, nullptr, nullptr, nullptr,
                                         nullptr, nullptr, nullptr, 0.f,
                                         Bq0, Bk0, Bv0, Bs0,
                                         bq, bk, bv, bskip,
                                         qbf, kvbf, xrbf, N);
    attn_gather<<<gNode16, blk, 0, stream>>>(qbf, kvbf, xrbf, rowptr, csr_sw,
                                             We, Wbeta, attnb,
                                             bstat0, bstat0 + 1024, N);
    // ---- BN(l0) fused into layer-1 4-projection GEMM (hbf never materialized) ----
    gemm4<1><<<gGemm4, blk, 0, stream>>>(nullptr, attnb, h, h,
                                         bstat0, bn_g, bn_b, invN,
                                         Bq1, Bk1, Bv1, Bs1,
                                         bq + 128, bk + 128, bv + 128, bskip + 128,
                                         qbf, kvbf, xrbf, N);
    attn_gather<<<gNode16, blk, 0, stream>>>(qbf, kvbf, xrbf, rowptr, csr_sw,
                                             We + 128, Wbeta + 384, attnb,
                                             bstat1, bstat1 + 1024, N);
    // ---- final BN + ReLU + residual -> d_out ----
    bn_apply<<<gApply, blk, 0, stream>>>(attnb, h, (float*)d_out,
                                         bstat1, bn_g + 128, bn_b + 128,
                                         N, invN);
}

// Round 10
// 300.404 us; speedup vs baseline: 1.0469x; 1.0279x over previous
//
#include <hip/hip_runtime.h>
#include <hip/hip_bf16.h>
#include <math.h>

#define EPS 1e-5f

typedef __attribute__((ext_vector_type(8))) short bf16x8;
typedef __attribute__((ext_vector_type(4))) float f32x4;

__device__ __forceinline__ unsigned short f2bf(float f) {
    unsigned u = __float_as_uint(f);
    unsigned r = (u + 0x7FFFu + ((u >> 16) & 1u)) >> 16;   // RNE
    return (unsigned short)r;
}
__device__ __forceinline__ unsigned f2bf2(float lo, float hi) {
    return (unsigned)f2bf(lo) | ((unsigned)f2bf(hi) << 16);
}
__device__ __forceinline__ void bfu2(unsigned u, float& lo, float& hi) {
    lo = __uint_as_float(u << 16);
    hi = __uint_as_float(u & 0xFFFF0000u);
}

// ---------- fused prep: x->bf16 | weight pack | deg zero + BN-stat zero ----------
__global__ __launch_bounds__(256) void prep(const float* __restrict__ x,
                                            unsigned short* __restrict__ xbf, int n4,
                                            const float* __restrict__ W0, const float* __restrict__ W1,
                                            const float* __restrict__ W2, const float* __restrict__ W3,
                                            const float* __restrict__ W4, const float* __restrict__ W5,
                                            const float* __restrict__ W6, const float* __restrict__ W7,
                                            const float* __restrict__ W8, unsigned short* __restrict__ Bpack,
                                            int* __restrict__ deg, float* __restrict__ bstatZ, int N,
                                            int nConv, int nPack) {
    int b = blockIdx.x;
    if (b < nConv) {
        int i = b * 256 + threadIdx.x;
        if (i < n4) {
            float4 v = ((const float4*)x)[i];
            ushort4 o = make_ushort4(f2bf(v.x), f2bf(v.y), f2bf(v.z), f2bf(v.w));
            ((ushort4*)xbf)[i] = o;
        }
    } else if (b < nConv + nPack) {
        int t = (b - nConv) * 256 + threadIdx.x;
        if (t < 9 * 16384) {
            int mat = t >> 14, r = t & 16383;
            const float* W;
            switch (mat) {
                case 0: W = W0; break; case 1: W = W1; break; case 2: W = W2; break;
                case 3: W = W3; break; case 4: W = W4; break; case 5: W = W5; break;
                case 6: W = W6; break; case 7: W = W7; break; default: W = W8; break;
            }
            int j = r & 7, lane = (r >> 3) & 63, nt = (r >> 9) & 7, kc = r >> 12;
            int k = kc * 32 + (lane >> 4) * 8 + j;
            int n = (lane & 15) * 8 + nt;
            Bpack[t] = f2bf(W[k * 128 + n]);
        }
    } else {
        int i = (b - nConv - nPack) * 256 + threadIdx.x;
        if (i < N) deg[i] = 0;
        if (i < 4096) bstatZ[i] = 0.f;   // both layers' stat replicas
    }
}

// ---------- input-projection MFMA GEMM: bf16 A -> ReLU -> bf16 out ONLY ----------
// (fp32 h dropped: residual is carried bf16; saves 25.6 MB of write traffic)
template <int ACT>
__global__ __launch_bounds__(256) void gemm_proj(const unsigned short* __restrict__ Abf,
                                                 const unsigned short* __restrict__ Bp,
                                                 const float* __restrict__ bias,
                                                 unsigned short* __restrict__ Cbf, int M) {
    int wave = threadIdx.x >> 6, lane = threadIdx.x & 63;
    int base = blockIdx.x * 64 + wave * 16;
    int m = lane & 15, kg = lane >> 4;
    int arow = base + m; if (arow >= M) arow = M - 1;
    const unsigned short* Aptr = Abf + (size_t)arow * 128 + kg * 8;
    f32x4 acc[8];
#pragma unroll
    for (int nt = 0; nt < 8; ++nt) acc[nt] = (f32x4)(0.f);
#pragma unroll
    for (int kc = 0; kc < 4; ++kc) {
        bf16x8 a = *(const bf16x8*)(Aptr + kc * 32);
        const unsigned short* bp = Bp + (size_t)kc * 4096 + (size_t)lane * 8;
#pragma unroll
        for (int nt = 0; nt < 8; ++nt) {
            bf16x8 b = *(const bf16x8*)(bp + nt * 512);
            acc[nt] = __builtin_amdgcn_mfma_f32_16x16x32_bf16(a, b, acc[nt], 0, 0, 0);
        }
    }
    int col0 = lane & 15;
    int r0 = base + (lane >> 4) * 4;
    float4 bl = *(const float4*)&bias[col0 * 8];
    float4 bh = *(const float4*)&bias[col0 * 8 + 4];
#pragma unroll
    for (int r = 0; r < 4; ++r) {
        int ro = r0 + r;
        if (ro < M) {
            float v0 = acc[0][r] + bl.x, v1 = acc[1][r] + bl.y;
            float v2 = acc[2][r] + bl.z, v3 = acc[3][r] + bl.w;
            float v4 = acc[4][r] + bh.x, v5 = acc[5][r] + bh.y;
            float v6 = acc[6][r] + bh.z, v7 = acc[7][r] + bh.w;
            if (ACT) {
                v0 = fmaxf(v0, 0.f); v1 = fmaxf(v1, 0.f); v2 = fmaxf(v2, 0.f); v3 = fmaxf(v3, 0.f);
                v4 = fmaxf(v4, 0.f); v5 = fmaxf(v5, 0.f); v6 = fmaxf(v6, 0.f); v7 = fmaxf(v7, 0.f);
            }
            size_t o = (size_t)ro * 128 + col0 * 8;
            *(uint4*)&Cbf[o] = make_uint4(f2bf2(v0, v1), f2bf2(v2, v3),
                                          f2bf2(v4, v5), f2bf2(v6, v7));
        }
    }
}

// ---------- 4-matrix fused GEMM (v13 partition: 32 rows/block, 2 matrices/wave) ----------
// wave w: rows base+(w&1)*16, matrix-pair (w>>1). acc = 64 VGPR, grid = ceil(M/32).
// BNPRO=1: BN(l-1) prologue on 32 rows; attn input bf16 (attnb), residual bf16
// (hres, updated IN PLACE to hout=new residual). Stats fp32. The packed bf16 r
// is written once to hout and once to LDS (same words).
// Rows >= M do nothing (v11 race lesson); their LDS slots are zero-filled.
template <int BNPRO>
__global__ __launch_bounds__(256) void gemm4(const unsigned short* __restrict__ Abf,
                                             const unsigned short* __restrict__ attnb,
                                             const unsigned short* __restrict__ hres,
                                             unsigned short* __restrict__ hout,
                                             const float* __restrict__ bstat,
                                             const float* __restrict__ gamma,
                                             const float* __restrict__ bbeta,
                                             float invN,
                                             const unsigned short* __restrict__ B0,
                                             const unsigned short* __restrict__ B1,
                                             const unsigned short* __restrict__ B2,
                                             const unsigned short* __restrict__ B3,
                                             const float* __restrict__ b0,
                                             const float* __restrict__ b1,
                                             const float* __restrict__ b2,
                                             const float* __restrict__ b3,
                                             unsigned short* __restrict__ qbf,
                                             unsigned short* __restrict__ kvbf,
                                             unsigned short* __restrict__ xrbf, int M) {
    __shared__ unsigned short As[32][136];   // +8 pad
    __shared__ float sMu[128], sGS[128], sB[128];
    int tid = threadIdx.x;
    int base = blockIdx.x * 32;

    if (BNPRO) {
        if (tid < 128) {
            float s = 0.f, q = 0.f;
#pragma unroll
            for (int rep = 0; rep < 8; ++rep) {
                s += bstat[rep * 128 + tid];
                q += bstat[1024 + rep * 128 + tid];
            }
            float mu = s * invN, var = q * invN - mu * mu;
            sMu[tid] = mu;
            sGS[tid] = gamma[tid] * rsqrtf(var + EPS);
            sB[tid] = bbeta[tid];
        }
        __syncthreads();
#pragma unroll
        for (int j = 0; j < 2; ++j) {
            int s = j * 256 + tid;            // 0..511 = 32 rows x 16 slots
            int row = s >> 4, sl = s & 15;
            int grow = base + row;
            if (grow < M) {
                size_t o = (size_t)grow * 128 + sl * 8;
                uint4 au = *(const uint4*)&attnb[o];
                float a0, a1, a2, a3, a4, a5, a6, a7;
                bfu2(au.x, a0, a1); bfu2(au.y, a2, a3);
                bfu2(au.z, a4, a5); bfu2(au.w, a6, a7);
                uint4 hu = *(const uint4*)&hres[o];
                float h0, h1, h2, h3, h4, h5, h6, h7;
                bfu2(hu.x, h0, h1); bfu2(hu.y, h2, h3);
                bfu2(hu.z, h4, h5); bfu2(hu.w, h6, h7);
                int c = sl * 8;
                float r0 = fmaxf((a0 - sMu[c+0]) * sGS[c+0] + sB[c+0], 0.f) + h0;
                float r1 = fmaxf((a1 - sMu[c+1]) * sGS[c+1] + sB[c+1], 0.f) + h1;
                float r2 = fmaxf((a2 - sMu[c+2]) * sGS[c+2] + sB[c+2], 0.f) + h2;
                float r3 = fmaxf((a3 - sMu[c+3]) * sGS[c+3] + sB[c+3], 0.f) + h3;
                float r4 = fmaxf((a4 - sMu[c+4]) * sGS[c+4] + sB[c+4], 0.f) + h4;
                float r5 = fmaxf((a5 - sMu[c+5]) * sGS[c+5] + sB[c+5], 0.f) + h5;
                float r6 = fmaxf((a6 - sMu[c+6]) * sGS[c+6] + sB[c+6], 0.f) + h6;
                float r7 = fmaxf((a7 - sMu[c+7]) * sGS[c+7] + sB[c+7], 0.f) + h7;
                uint4 rb = make_uint4(f2bf2(r0, r1), f2bf2(r2, r3),
                                      f2bf2(r4, r5), f2bf2(r6, r7));
                *(uint4*)&hout[o] = rb;            // new bf16 residual, in place
                *(uint4*)&As[row][sl * 8] = rb;    // same words as GEMM A operand
            } else {
                *(uint4*)&As[row][sl * 8] = make_uint4(0u, 0u, 0u, 0u);
            }
        }
        __syncthreads();
    }

    int wave = tid >> 6, lane = tid & 63;
    int rg = wave & 1;              // row group (0..1)
    int mp = wave >> 1;             // matrix pair (0: q/k, 1: v/skip)
    int wbase = base + rg * 16;
    int m = lane & 15, kg = lane >> 4;
    const unsigned short* Aptr = 0;
    if (!BNPRO) {
        int arow = wbase + m; if (arow >= M) arow = M - 1;
        Aptr = Abf + (size_t)arow * 128 + kg * 8;
    }
    const unsigned short* Bx = mp ? B2 : B0;
    const unsigned short* By = mp ? B3 : B1;
    f32x4 ax[8], ay[8];
#pragma unroll
    for (int nt = 0; nt < 8; ++nt) { ax[nt] = (f32x4)(0.f); ay[nt] = (f32x4)(0.f); }
#pragma unroll
    for (int kc = 0; kc < 4; ++kc) {
        bf16x8 a;
        if (BNPRO) a = *(const bf16x8*)&As[rg * 16 + m][kg * 8 + kc * 32];
        else       a = *(const bf16x8*)(Aptr + kc * 32);
        size_t boff = (size_t)kc * 4096 + (size_t)lane * 8;
#pragma unroll
        for (int nt = 0; nt < 8; ++nt) {
            bf16x8 wx = *(const bf16x8*)(Bx + boff + nt * 512);
            ax[nt] = __builtin_amdgcn_mfma_f32_16x16x32_bf16(a, wx, ax[nt], 0, 0, 0);
            bf16x8 wy = *(const bf16x8*)(By + boff + nt * 512);
            ay[nt] = __builtin_amdgcn_mfma_f32_16x16x32_bf16(a, wy, ay[nt], 0, 0, 0);
        }
    }
    int col0 = lane & 15;
    int r0r = wbase + (lane >> 4) * 4;
    const float* bxp = mp ? b2 : b0;
    const float* byp = mp ? b3 : b1;
    float4 bxl = *(const float4*)&bxp[col0 * 8], bxh = *(const float4*)&bxp[col0 * 8 + 4];
    float4 byl = *(const float4*)&byp[col0 * 8], byh = *(const float4*)&byp[col0 * 8 + 4];
#pragma unroll
    for (int r = 0; r < 4; ++r) {
        int ro = r0r + r;
        if (ro < M) {
            size_t qo = (size_t)ro * 128 + col0 * 8;
            size_t kvo = (size_t)ro * 256 + col0 * 8;
            uint4 ox = make_uint4(
                f2bf2(ax[0][r] + bxl.x, ax[1][r] + bxl.y), f2bf2(ax[2][r] + bxl.z, ax[3][r] + bxl.w),
                f2bf2(ax[4][r] + bxh.x, ax[5][r] + bxh.y), f2bf2(ax[6][r] + bxh.z, ax[7][r] + bxh.w));
            uint4 oy = make_uint4(
                f2bf2(ay[0][r] + byl.x, ay[1][r] + byl.y), f2bf2(ay[2][r] + byl.z, ay[3][r] + byl.w),
                f2bf2(ay[4][r] + byh.x, ay[5][r] + byh.y), f2bf2(ay[6][r] + byh.z, ay[7][r] + byh.w));
            if (mp == 0) {
                *(uint4*)&qbf[qo] = ox;           // q
                *(uint4*)&kvbf[kvo] = oy;         // k
            } else {
                *(uint4*)&kvbf[kvo + 128] = ox;   // v
                *(uint4*)&xrbf[qo] = oy;          // skip
            }
        }
    }
}

// ---------- CSR build ----------
__global__ __launch_bounds__(256) void csr_hist(const int* __restrict__ ei,
                                                int* __restrict__ deg, int E) {
    int e = blockIdx.x * 256 + threadIdx.x;
    if (e < E) atomicAdd(&deg[ei[E + e]], 1);
}

__global__ __launch_bounds__(256) void scan_block_sums(const int* __restrict__ deg,
                                                       int* __restrict__ bsums, int N) {
    __shared__ int sd[256];
    int i = blockIdx.x * 256 + threadIdx.x;
    sd[threadIdx.x] = (i < N) ? deg[i] : 0;
    __syncthreads();
    for (int off = 128; off > 0; off >>= 1) {
        if (threadIdx.x < off) sd[threadIdx.x] += sd[threadIdx.x + off];
        __syncthreads();
    }
    if (threadIdx.x == 0) bsums[blockIdx.x] = sd[0];
}

__global__ __launch_bounds__(256) void scan_bsums(const int* __restrict__ bsums,
                                                  int* __restrict__ boff, int nb) {
    __shared__ int sd[256];
    int tid = threadIdx.x;
    int per = (nb + 255) / 256;
    int start = tid * per;
    int s = 0;
    for (int i = 0; i < per; ++i) {
        int idx = start + i;
        if (idx < nb) s += bsums[idx];
    }
    int my = s;
    sd[tid] = s;
    __syncthreads();
    for (int off = 1; off < 256; off <<= 1) {
        int t = (tid >= off) ? sd[tid - off] : 0;
        __syncthreads();
        sd[tid] += t;
        __syncthreads();
    }
    int run = sd[tid] - my;
    for (int i = 0; i < per; ++i) {
        int idx = start + i;
        if (idx < nb) {
            boff[idx] = run;
            run += bsums[idx];
        }
    }
}

__global__ __launch_bounds__(256) void scan_local(const int* __restrict__ deg,
                                                  const int* __restrict__ boff,
                                                  int* __restrict__ rowptr,
                                                  int* __restrict__ wrptr, int N, int E) {
    __shared__ int sd[256];
    int i = blockIdx.x * 256 + threadIdx.x;
    int v = (i < N) ? deg[i] : 0;
    sd[threadIdx.x] = v;
    __syncthreads();
    for (int off = 1; off < 256; off <<= 1) {
        int t = (threadIdx.x >= off) ? sd[threadIdx.x - off] : 0;
        __syncthreads();
        sd[threadIdx.x] += t;
        __syncthreads();
    }
    if (i < N) {
        int excl = sd[threadIdx.x] - v + boff[blockIdx.x];
        rowptr[i] = excl;
        wrptr[i] = excl;
        if (i == N - 1) rowptr[N] = E;
    }
}

__global__ __launch_bounds__(256) void csr_fill(const int* __restrict__ ei,
                                                const float* __restrict__ ea,
                                                int* __restrict__ wrptr,
                                                int2* __restrict__ csr_sw, int E) {
    int e = blockIdx.x * 256 + threadIdx.x;
    if (e >= E) return;
    int tgt = ei[E + e];
    int pos = atomicAdd(&wrptr[tgt], 1);
    csr_sw[pos] = make_int2(ei[e], __float_as_int(ea[e]));
}

// ---------- attention gather (v10 structure), OUT = bf16 ----------
__global__ __launch_bounds__(256) void attn_gather(const unsigned short* __restrict__ qbf,
                                                   const unsigned short* __restrict__ kvbf,
                                                   const unsigned short* __restrict__ xrbf,
                                                   const int* __restrict__ rowptr,
                                                   const int2* __restrict__ csr_sw,
                                                   const float* __restrict__ Wel,
                                                   const float* __restrict__ Wb,
                                                   unsigned short* __restrict__ out,
                                                   float* __restrict__ bsumR,
                                                   float* __restrict__ bsumsqR, int N) {
    __shared__ float sdS[4][128];
    __shared__ float sdQ[4][128];
    int tid = threadIdx.x;
    int n = blockIdx.x * 16 + (tid >> 4);
    int sl = tid & 15;
    int wave = tid >> 6, lane = tid & 63;
    bool live = (n < N);
    int nn = live ? n : (N - 1);

    uint4 qu = ((const uint4*)(qbf + (size_t)nn * 128))[sl];
    float qf[8];
    bfu2(qu.x, qf[0], qf[1]); bfu2(qu.y, qf[2], qf[3]);
    bfu2(qu.z, qf[4], qf[5]); bfu2(qu.w, qf[6], qf[7]);
    float wef[8];
    {
        float4 w0 = ((const float4*)Wel)[sl * 2];
        float4 w1 = ((const float4*)Wel)[sl * 2 + 1];
        wef[0] = w0.x; wef[1] = w0.y; wef[2] = w0.z; wef[3] = w0.w;
        wef[4] = w1.x; wef[5] = w1.y; wef[6] = w1.z; wef[7] = w1.w;
    }
    float qwe = 0.f;
#pragma unroll
    for (int c = 0; c < 8; ++c) qwe += qf[c] * wef[c];
    qwe += __shfl_xor(qwe, 1);
    qwe += __shfl_xor(qwe, 2);

    float l = 0.f, pw = 0.f;
    float acc[8];
#pragma unroll
    for (int c = 0; c < 8; ++c) acc[c] = 0.f;

    int beg = live ? rowptr[nn] : 0;
    int end = live ? rowptr[nn + 1] : 0;

    if (beg < end) {
        int2 sw0 = csr_sw[beg];
        int j1 = (beg + 1 < end) ? beg + 1 : beg;
        int2 sw1 = csr_sw[j1];
        int j2 = (beg + 2 < end) ? beg + 2 : beg;
        int2 sw2 = csr_sw[j2];
        const uint4* r0 = (const uint4*)(kvbf + (size_t)sw0.x * 256);
        uint4 ku0 = r0[sl], vu0 = r0[16 + sl];
        const uint4* r1 = (const uint4*)(kvbf + (size_t)sw1.x * 256);
        uint4 ku1 = r1[sl], vu1 = r1[16 + sl];

        for (int i = beg; i < end; ++i) {
            const uint4* r2 = (const uint4*)(kvbf + (size_t)sw2.x * 256);
            uint4 ku2 = r2[sl], vu2 = r2[16 + sl];
            int j3 = (i + 3 < end) ? i + 3 : beg;
            int2 sw3 = csr_sw[j3];

            float w = __int_as_float(sw0.y);
            float kf[8];
            bfu2(ku0.x, kf[0], kf[1]); bfu2(ku0.y, kf[2], kf[3]);
            bfu2(ku0.z, kf[4], kf[5]); bfu2(ku0.w, kf[6], kf[7]);
            float d = 0.f;
#pragma unroll
            for (int c = 0; c < 8; ++c) d += qf[c] * kf[c];
            d += __shfl_xor(d, 1); d += __shfl_xor(d, 2);
            float p = __expf((d + w * qwe) * 0.17677669529663687f);
            l += p;
            pw += p * w;
            float vf[8];
            bfu2(vu0.x, vf[0], vf[1]); bfu2(vu0.y, vf[2], vf[3]);
            bfu2(vu0.z, vf[4], vf[5]); bfu2(vu0.w, vf[6], vf[7]);
#pragma unroll
            for (int c = 0; c < 8; ++c)
                acc[c] += p * vf[c];

            sw0 = sw1; sw1 = sw2; sw2 = sw3;
            ku0 = ku1; vu0 = vu1;
            ku1 = ku2; vu1 = vu2;
        }
    }

    float inv = (l > 0.f) ? 1.f / l : 0.f;
    float ox[8];
#pragma unroll
    for (int c = 0; c < 8; ++c) ox[c] = (acc[c] + pw * wef[c]) * inv;

    uint4 xu = ((const uint4*)(xrbf + (size_t)nn * 128))[sl];
    float xv[8];
    bfu2(xu.x, xv[0], xv[1]); bfu2(xu.y, xv[2], xv[3]);
    bfu2(xu.z, xv[4], xv[5]); bfu2(xu.w, xv[6], xv[7]);
    float4 b0 = ((const float4*)Wb)[sl * 2];
    float4 b1 = ((const float4*)Wb)[sl * 2 + 1];
    float4 c0 = ((const float4*)(Wb + 128))[sl * 2];
    float4 c1 = ((const float4*)(Wb + 128))[sl * 2 + 1];
    float4 d0 = ((const float4*)(Wb + 256))[sl * 2];
    float4 d1 = ((const float4*)(Wb + 256))[sl * 2 + 1];
    float wb0[8] = {b0.x, b0.y, b0.z, b0.w, b1.x, b1.y, b1.z, b1.w};
    float wb1[8] = {c0.x, c0.y, c0.z, c0.w, c1.x, c1.y, c1.z, c1.w};
    float wb2[8] = {d0.x, d0.y, d0.z, d0.w, d1.x, d1.y, d1.z, d1.w};
    float part = 0.f;
#pragma unroll
    for (int c = 0; c < 8; ++c)
        part += ox[c] * wb0[c] + xv[c] * wb1[c] + (ox[c] - xv[c]) * wb2[c];
    part += __shfl_xor(part, 1); part += __shfl_xor(part, 2);
    part += __shfl_xor(part, 4); part += __shfl_xor(part, 8);
    float beta = 1.f / (1.f + __expf(-part));

    float r[8];
#pragma unroll
    for (int c = 0; c < 8; ++c)
        r[c] = beta * xv[c] + (1.f - beta) * ox[c];

    if (live) {
        *(uint4*)&out[(size_t)n * 128 + sl * 8] =
            make_uint4(f2bf2(r[0], r[1]), f2bf2(r[2], r[3]),
                       f2bf2(r[4], r[5]), f2bf2(r[6], r[7]));
    }

    // ---- fused BN stats on fp32 r (LDS stage + 2 atomics/thread for tid<128) ----
    float s8[8], q8[8];
#pragma unroll
    for (int c = 0; c < 8; ++c) {
        s8[c] = live ? r[c] : 0.f;
        q8[c] = live ? r[c] * r[c] : 0.f;
    }
#pragma unroll
    for (int c = 0; c < 8; ++c) {
        s8[c] += __shfl_xor(s8[c], 16); s8[c] += __shfl_xor(s8[c], 32);
        q8[c] += __shfl_xor(q8[c], 16); q8[c] += __shfl_xor(q8[c], 32);
    }
    if ((lane >> 4) == 0) {
#pragma unroll
        for (int c = 0; c < 8; ++c) {
            sdS[wave][sl * 8 + c] = s8[c];
            sdQ[wave][sl * 8 + c] = q8[c];
        }
    }
    __syncthreads();
    if (tid < 128) {
        float s = sdS[0][tid] + sdS[1][tid] + sdS[2][tid] + sdS[3][tid];
        float q = sdQ[0][tid] + sdQ[1][tid] + sdQ[2][tid] + sdQ[3][tid];
        int rep = blockIdx.x & 7;
        atomicAdd(&bsumR[rep * 128 + tid], s);
        atomicAdd(&bsumsqR[rep * 128 + tid], q);
    }
}

// ---------- BN apply + ReLU + residual (final layer, bf16 attn + bf16 residual in) ----------
__global__ __launch_bounds__(256) void bn_apply(const unsigned short* __restrict__ o,
                                                const unsigned short* __restrict__ hres,
                                                float* __restrict__ hout,
                                                const float* __restrict__ bstat,
                                                const float* __restrict__ gamma,
                                                const float* __restrict__ bbeta,
                                                int N, float invN) {
    int i = blockIdx.x * 256 + threadIdx.x;
    if (i >= N * 32) return;
    int c4 = i & 31;
    float4 s = make_float4(0.f, 0.f, 0.f, 0.f), ss = s;
#pragma unroll
    for (int rep = 0; rep < 8; ++rep) {
        float4 sv = ((const float4*)bstat)[rep * 32 + c4];
        float4 qv = ((const float4*)(bstat + 1024))[rep * 32 + c4];
        s.x += sv.x; s.y += sv.y; s.z += sv.z; s.w += sv.w;
        ss.x += qv.x; ss.y += qv.y; ss.z += qv.z; ss.w += qv.w;
    }
    float4 g = ((const float4*)gamma)[c4];
    float4 b = ((const float4*)bbeta)[c4];
    uint2 ou = *(const uint2*)&o[(size_t)i * 4];
    float o0, o1, o2, o3;
    bfu2(ou.x, o0, o1); bfu2(ou.y, o2, o3);
    uint2 hu = *(const uint2*)&hres[(size_t)i * 4];
    float h0, h1, h2, h3;
    bfu2(hu.x, h0, h1); bfu2(hu.y, h2, h3);
    float4 r;
    { float mu = s.x * invN, var = ss.x * invN - mu * mu;
      r.x = fmaxf((o0 - mu) * (g.x * rsqrtf(var + EPS)) + b.x, 0.f) + h0; }
    { float mu = s.y * invN, var = ss.y * invN - mu * mu;
      r.y = fmaxf((o1 - mu) * (g.y * rsqrtf(var + EPS)) + b.y, 0.f) + h1; }
    { float mu = s.z * invN, var = ss.z * invN - mu * mu;
      r.z = fmaxf((o2 - mu) * (g.z * rsqrtf(var + EPS)) + b.z, 0.f) + h2; }
    { float mu = s.w * invN, var = ss.w * invN - mu * mu;
      r.w = fmaxf((o3 - mu) * (g.w * rsqrtf(var + EPS)) + b.w, 0.f) + h3; }
    ((float4*)hout)[i] = r;
}

extern "C" void kernel_launch(void* const* d_in, const int* in_sizes, int n_in,
                              void* d_out, int out_size, void* d_ws, size_t ws_size,
                              hipStream_t stream) {
    const float* x     = (const float*)d_in[0];
    const int*   ei    = (const int*)d_in[1];
    const float* ea    = (const float*)d_in[2];
    const float* W_in  = (const float*)d_in[3];
    const float* b_in  = (const float*)d_in[4];
    const float* Wq    = (const float*)d_in[5];
    const float* bq    = (const float*)d_in[6];
    const float* Wk    = (const float*)d_in[7];
    const float* bk    = (const float*)d_in[8];
    const float* Wv    = (const float*)d_in[9];
    const float* bv    = (const float*)d_in[10];
    const float* We    = (const float*)d_in[11];
    const float* Wskip = (const float*)d_in[12];
    const float* bskip = (const float*)d_in[13];
    const float* Wbeta = (const float*)d_in[14];
    const float* bn_g  = (const float*)d_in[15];
    const float* bn_b  = (const float*)d_in[16];

    const int N = in_sizes[0] / 128;
    const int E = in_sizes[1] / 2;

    float* ws = (float*)d_ws;
    unsigned short* Bpack = (unsigned short*)ws;           // 9*16384 bf16 = 73728 floats
    size_t off = 73728;
    unsigned short* xbf  = (unsigned short*)(ws + off);               off += (size_t)N * 64;
    unsigned short* hbf  = (unsigned short*)(ws + off);               off += (size_t)N * 64;   // bf16 residual
    unsigned short* qbf  = (unsigned short*)(ws + off);               off += (size_t)N * 64;
    unsigned short* kvbf = (unsigned short*)(ws + off);               off += (size_t)N * 128;
    unsigned short* xrbf = (unsigned short*)(ws + off);               off += (size_t)N * 64;
    unsigned short* attnb = (unsigned short*)(ws + off);  off += (size_t)N * 64;   // bf16 attn
    float* bstat = ws + off; off += 4096;                  // [l0: sumR1024|sumsq1024][l1: ...]
    int2* csr_sw = (int2*)(ws + off);  off += (size_t)E * 2;
    int* deg     = (int*)(ws + off);
    int* rowptr  = deg + N;
    int* wrptr   = rowptr + (N + 1);
    int* bsums   = wrptr + N;
    int* boff    = bsums + ((N + 255) / 256 + 1);

    float* bstat0 = bstat;
    float* bstat1 = bstat + 2048;

    dim3 blk(256);
    int gGemm   = (N + 63) / 64;
    int gGemm4  = (N + 31) / 32;
    int gNode16 = (N + 15) / 16;
    int gEdge   = (E + 255) / 256;
    int gApply  = (N * 32 + 255) / 256;
    int nbScan  = (N + 255) / 256;
    float invN = 1.0f / (float)N;

    // ---- fused prep: x->bf16 | weight pack | deg+stat zero ----
    int nConv = gApply;
    int nPack = (9 * 16384 + 255) / 256;
    prep<<<nConv + nPack + nbScan, blk, 0, stream>>>(
        x, xbf, N * 32,
        W_in, Wq, Wk, Wv, Wskip, Wq + 16384, Wk + 16384, Wv + 16384, Wskip + 16384,
        Bpack, deg, bstat, N, nConv, nPack);

    // ---- CSR build ----
    csr_hist<<<gEdge, blk, 0, stream>>>(ei, deg, E);
    scan_block_sums<<<nbScan, blk, 0, stream>>>(deg, bsums, N);
    scan_bsums<<<1, blk, 0, stream>>>(bsums, boff, nbScan);
    scan_local<<<nbScan, blk, 0, stream>>>(deg, boff, rowptr, wrptr, N, E);
    csr_fill<<<gEdge, blk, 0, stream>>>(ei, ea, wrptr, csr_sw, E);

    // ---- input projection (writes bf16 residual hbf only) ----
    gemm_proj<1><<<gGemm, blk, 0, stream>>>(xbf, Bpack + 0 * 16384, b_in, hbf, N);

    const unsigned short* Bq0 = Bpack + (size_t)1 * 16384;
    const unsigned short* Bk0 = Bpack + (size_t)2 * 16384;
    const unsigned short* Bv0 = Bpack + (size_t)3 * 16384;
    const unsigned short* Bs0 = Bpack + (size_t)4 * 16384;
    const unsigned short* Bq1 = Bpack + (size_t)5 * 16384;
    const unsigned short* Bk1 = Bpack + (size_t)6 * 16384;
    const unsigned short* Bv1 = Bpack + (size_t)7 * 16384;
    const unsigned short* Bs1 = Bpack + (size_t)8 * 16384;

    // ---- layer 0: 4-projection GEMM (A = hbf) ----
    gemm4<0><<<gGemm4, blk, 0, stream>>>(hbf, nullptr, nullptr, nullptr,
                                         nullptr, nullptr, nullptr, 0.f,
                                         Bq0, Bk0, Bv0, Bs0,
                                         bq, bk, bv, bskip,
                                         qbf, kvbf, xrbf, N);
    attn_gather<<<gNode16, blk, 0, stream>>>(qbf, kvbf, xrbf, rowptr, csr_sw,
                                             We, Wbeta, attnb,
                                             bstat0, bstat0 + 1024, N);
    // ---- BN(l0) fused into layer-1 4-projection GEMM; hbf updated in place ----
    gemm4<1><<<gGemm4, blk, 0, stream>>>(nullptr, attnb, hbf, hbf,
                                         bstat0, bn_g, bn_b, invN,
                                         Bq1, Bk1, Bv1, Bs1,
                                         bq + 128, bk + 128, bv + 128, bskip + 128,
                                         qbf, kvbf, xrbf, N);
    attn_gather<<<gNode16, blk, 0, stream>>>(qbf, kvbf, xrbf, rowptr, csr_sw,
                                             We + 128, Wbeta + 384, attnb,
                                             bstat1, bstat1 + 1024, N);
    // ---- final BN + ReLU + residual -> d_out ----
    bn_apply<<<gApply, blk, 0, stream>>>(attnb, hbf, (float*)d_out,
                                         bstat1, bn_g + 128, bn_b + 128,
                                         N, invN);
}